// Round 5
// baseline (172.122 us; speedup 1.0000x reference)
//
#include <hip/hip_runtime.h>

#define LN_EPS 1e-5f
#define SBSH   14             // superbucket = dst >> 14 (16384 nodes)
#define NSB    7              // ceil(100000 / 16384)
#define CAP1   268288         // per-SB capacity = 131*2048 (mean 262144 + ~13 sigma)
#define CPS    131            // CAP1 / 2048 chunks per SB (bin2 chunking)
#define BN     128            // nodes per final bucket
#define BC     2368           // bucket capacity (mean 2048 + 7 sigma, R8-proven)
#define SCAP   2752           // BC + 128*3 (per-bin pad to multiple of 4)
#define NBK    782            // ceil(N / BN)
#define CSTRIDE 8
#define ASTR   72             // aggS row stride in bf16 (144 B -> 4-bank row shift, 2-way max)

typedef __attribute__((ext_vector_type(8))) short short8;
typedef __attribute__((ext_vector_type(8))) unsigned short ushort8;
typedef __attribute__((ext_vector_type(4))) float v4f;

__device__ __forceinline__ unsigned short f2bf(float f) {
    union { float f; unsigned u; } v; v.f = f;
    unsigned r = (v.u + 0x7fffu + ((v.u >> 16) & 1u)) >> 16;   // RNE
    return (unsigned short)r;
}
__device__ __forceinline__ float bf2f(unsigned short h) {
    union { unsigned u; float f; } v; v.u = ((unsigned)h) << 16;
    return v.f;
}

// ---------------- bin1: edges -> 7 superbuckets (+ WTB + x->bf16 + zero row) --------
__global__ __launch_bounds__(256) void bin1_kernel(
    const int* __restrict__ ei, int* __restrict__ cursor1,
    int* __restrict__ pairs1, const float* __restrict__ W,
    unsigned short* __restrict__ WTB, const float4* __restrict__ x4,
    ushort4* __restrict__ xb4, int E, int N)
{
    __shared__ int h[64];       // [copy*8 + sb]
    __shared__ int hbase[64];
    int t = threadIdx.x;
    int cp = t & 7;

    if (blockIdx.x == 0) {
        // WTB: frag (s,tt), lane l, elem j <- W[o=tt*16+(l&15)][k=s*32+(l>>4)*8+j]
        for (int i = t; i < 8192; i += 256) {
            int j = i & 7, l = (i >> 3) & 63, st = i >> 9;
            int s = st >> 2, tt = st & 3;
            WTB[i] = f2bf(W[(tt * 16 + (l & 15)) * 128 + s * 32 + (l >> 4) * 8 + j]);
        }
        if (t < 16) {           // zero-row sentinel at row N (srcS hole target)
            ushort4 z; z.x = 0; z.y = 0; z.z = 0; z.w = 0;
            xb4[(size_t)N * 16 + t] = z;
        }
    }
    {   // grid-stride x -> bf16
        int total4 = N * 16;
        for (int i = blockIdx.x * 256 + t; i < total4; i += gridDim.x * 256) {
            float4 v = x4[i];
            ushort4 u;
            u.x = f2bf(v.x); u.y = f2bf(v.y); u.z = f2bf(v.z); u.w = f2bf(v.w);
            xb4[i] = u;
        }
    }

    for (int i = t; i < 64; i += 256) h[i] = 0;
    __syncthreads();
    int e0 = blockIdx.x * 4096;
    int dstA[16], srcA[16], rkA[16];
    #pragma unroll
    for (int i = 0; i < 16; ++i) {
        int e = e0 + i * 256 + t;
        int dst = 0, src = 0, rk = -1;
        if (e < E) {
            dst = ei[e]; src = ei[E + e];
            if ((unsigned)dst < (unsigned)N) {
                rk = atomicAdd(&h[cp * 8 + (dst >> SBSH)], 1);
                if ((unsigned)src >= (unsigned)N) src = 0;   // replay-safe clamp
            } else { dst = 0; }
        }
        dstA[i] = dst; srcA[i] = src; rkA[i] = rk;
    }
    __syncthreads();
    if (t < 8) {    // per sb: total over copies, one global reservation, copy prefixes
        int tot = 0;
        #pragma unroll
        for (int c = 0; c < 8; ++c) tot += h[c * 8 + t];
        int gb = tot ? atomicAdd(&cursor1[t * 16], tot) : 0;
        int run = gb;
        #pragma unroll
        for (int c = 0; c < 8; ++c) { hbase[c * 8 + t] = run; run += h[c * 8 + t]; }
    }
    __syncthreads();
    #pragma unroll
    for (int i = 0; i < 16; ++i) {
        if (rkA[i] >= 0) {
            int sb = dstA[i] >> SBSH;
            int slot = hbase[cp * 8 + sb] + rkA[i];
            if (slot < CAP1)
                pairs1[(size_t)sb * CAP1 + slot] = ((dstA[i] & 16383) << 17) | srcA[i];
        }
    }
}

// ---------------- bin2: superbucket chunk -> 128-node buckets ----------------
__global__ __launch_bounds__(256) void bin2_kernel(
    const int* __restrict__ cursor1, const int* __restrict__ pairs1,
    int* __restrict__ cursor2, int* __restrict__ pairs2)
{
    __shared__ int h[128], hbase[128];
    int t = threadIdx.x;
    int sb = blockIdx.x / CPS;
    int off0 = (blockIdx.x % CPS) * 2048;
    int tot = cursor1[sb * 16]; if (tot > CAP1) tot = CAP1;
    int m = tot - off0;
    if (m <= 0) return;                    // block-uniform
    if (m > 2048) m = 2048;
    if (t < 128) h[t] = 0;
    __syncthreads();
    const int* p1 = pairs1 + (size_t)sb * CAP1 + off0;
    int pvA[8], rkA[8];
    #pragma unroll
    for (int i = 0; i < 8; ++i) {
        int idx = i * 256 + t;
        int pv = 0, rk = -1;
        if (idx < m) { pv = p1[idx]; rk = atomicAdd(&h[(pv >> 24) & 127], 1); }
        pvA[i] = pv; rkA[i] = rk;
    }
    __syncthreads();
    if (t < 128) {
        int c = h[t];
        hbase[t] = c ? atomicAdd(&cursor2[(sb * 128 + t) * CSTRIDE], c) : 0;
    }
    __syncthreads();
    #pragma unroll
    for (int i = 0; i < 8; ++i) {
        if (rkA[i] >= 0) {
            int bl = (pvA[i] >> 24) & 127;
            int g = sb * 128 + bl;
            int slot = hbase[bl] + rkA[i];
            if (g < NBK && slot < BC)
                pairs2[(size_t)g * BC + slot] = pvA[i] & 0xFFFFFF;
        }
    }
}

// ---- fused sortgather + linear + ReLU + LN (v4: quad-index, zero-row, pipelined) ----
// Round-4 post-mortem: compiler kept VGPR=32 and sank the loads (shallow depth);
// mask FMAs were pure overhead. v4 removes the three measured inefficiencies:
//  (a) per-edge broadcast ds_read_b32 of srcS -> ONE ds_read_b128 per 4 edges
//      (bin bases 16-B aligned by padding bin sizes to x4 in the scan);
//  (b) mask FMAs -> gone: srcS holes pre-filled with the zero-row index N, so
//      padded slots load an all-zeros (L1-hot) row and plain-add 0;
//  (c) shallow ILP -> explicit 2-stage pipeline: batch j+4's 4 row-loads issue
//      before batch j is consumed (8 rows in flight/wave, ~55 VGPR <= 64).
__global__ __launch_bounds__(1024, 8) void sortgather_kernel(
    const int* __restrict__ cursor2, const int* __restrict__ pairs2,
    const unsigned short* __restrict__ xb, const unsigned short* __restrict__ WTB,
    const float* __restrict__ b, const float* __restrict__ gamma,
    const float* __restrict__ beta, float* __restrict__ out, int N)
{
    __shared__ __align__(16) int srcS[SCAP];         // 11 KB
    __shared__ int cnt[BN], off[BN];                 // 1 KB
    __shared__ __align__(16) unsigned short aggS[BN * ASTR];   // 18 KB
    int t = threadIdx.x;
    int g = blockIdx.x;
    int bsize = cursor2[g * CSTRIDE]; if (bsize > BC) bsize = BC;
    const int* pb = pairs2 + (size_t)g * BC;

    if (t < BN) cnt[t] = 0;
    for (int i = t; i < SCAP; i += 1024) srcS[i] = N;   // holes -> zero-row sentinel
    __syncthreads();
    // single histogram+rank pass (pb read ONCE; rank kept in registers)
    int pvA[3], rkA[3];
    #pragma unroll
    for (int i = 0; i < 3; ++i) {
        int idx = i * 1024 + t;
        int pv = 0, rk = -1;
        if (idx < bsize) { pv = pb[idx]; rk = atomicAdd(&cnt[(pv >> 17) & 127], 1); }
        pvA[i] = pv; rkA[i] = rk;
    }
    __syncthreads();
    // wave 0: exclusive prefix over 128 bins of PADDED counts (x4 -> 16-B bases)
    if (t < 64) {
        int c0 = (cnt[t] + 3) & ~3, c1 = (cnt[t + 64] + 3) & ~3;
        int v0 = c0, v1 = c1;
        #pragma unroll
        for (int d = 1; d < 64; d <<= 1) {
            int u0 = __shfl_up(v0, d);
            int u1 = __shfl_up(v1, d);
            if (t >= d) { v0 += u0; v1 += u1; }
        }
        int tot0 = __shfl(v0, 63);
        off[t]      = v0 - c0;
        off[t + 64] = v1 - c1 + tot0;
    }
    __syncthreads();
    #pragma unroll
    for (int i = 0; i < 3; ++i) {
        if (rkA[i] >= 0) {
            int bl = (pvA[i] >> 17) & 127;
            srcS[off[bl] + rkA[i]] = pvA[i] & 0x1FFFF;
        }
    }
    __syncthreads();

    int lane = t & 63, wv = t >> 6;          // 16 waves x 8 groups = 128 nodes
    int g8 = lane >> 3, f8 = lane & 7;
    int ln = wv * 8 + g8;                    // this group's node (bucket-local)
    int deg = cnt[ln], base = off[ln];
    int pdeg = (deg + 3) & ~3;               // padded trip count (holes add +0.0)

    float acc[8];
    #pragma unroll
    for (int k = 0; k < 8; ++k) acc[k] = 0.f;

    const unsigned short* xf = xb + (size_t)f8 * 8;

    short8 A0, A1, A2, A3;
    if (pdeg > 0) {                          // prologue: batch 0 in flight
        int4 ix = *(const int4*)(srcS + base);
        A0 = *(const short8*)(xf + (size_t)ix.x * 64);
        A1 = *(const short8*)(xf + (size_t)ix.y * 64);
        A2 = *(const short8*)(xf + (size_t)ix.z * 64);
        A3 = *(const short8*)(xf + (size_t)ix.w * 64);
    }
    for (int j = 4; j < pdeg; j += 4) {      // steady state: issue j, consume j-4
        int4 ix = *(const int4*)(srcS + base + j);
        short8 B0 = *(const short8*)(xf + (size_t)ix.x * 64);
        short8 B1 = *(const short8*)(xf + (size_t)ix.y * 64);
        short8 B2 = *(const short8*)(xf + (size_t)ix.z * 64);
        short8 B3 = *(const short8*)(xf + (size_t)ix.w * 64);
        #pragma unroll
        for (int e = 0; e < 8; ++e) acc[e] += bf2f((unsigned short)A0[e]);
        #pragma unroll
        for (int e = 0; e < 8; ++e) acc[e] += bf2f((unsigned short)A1[e]);
        #pragma unroll
        for (int e = 0; e < 8; ++e) acc[e] += bf2f((unsigned short)A2[e]);
        #pragma unroll
        for (int e = 0; e < 8; ++e) acc[e] += bf2f((unsigned short)A3[e]);
        A0 = B0; A1 = B1; A2 = B2; A3 = B3;
    }
    if (pdeg > 0) {                          // epilogue: last batch
        #pragma unroll
        for (int e = 0; e < 8; ++e) acc[e] += bf2f((unsigned short)A0[e]);
        #pragma unroll
        for (int e = 0; e < 8; ++e) acc[e] += bf2f((unsigned short)A1[e]);
        #pragma unroll
        for (int e = 0; e < 8; ++e) acc[e] += bf2f((unsigned short)A2[e]);
        #pragma unroll
        for (int e = 0; e < 8; ++e) acc[e] += bf2f((unsigned short)A3[e]);
    }

    {   // agg (mean) -> LDS bf16, row = bucket-local node, stride 72
        float inv = 1.0f / fmaxf((float)deg, 1.0f);
        ushort8 r;
        #pragma unroll
        for (int k = 0; k < 8; ++k) r[k] = f2bf(acc[k] * inv);
        *(ushort8*)(aggS + ln * ASTR + f8 * 8) = r;   // 144-B rows: 16-B aligned
    }
    __syncthreads();

    // ---- linear epilogue: waves 0..7, wave wv -> nodes [g*128+wv*16, +16) ----
    if (wv < 8) {
        int c = lane & 15, q = lane >> 4;
        int nb = g * BN + wv * 16;
        int nm = nb + c; if (nm >= N) nm = N - 1;
        int lnl = wv * 16 + c;               // bucket-local node for aggS

        const short8* WB = (const short8*)WTB;
        v4f acc4[4];
        #pragma unroll
        for (int tt = 0; tt < 4; ++tt) acc4[tt] = 0.f;

        #pragma unroll
        for (int s = 0; s < 2; ++s) {
            short8 af = *(const short8*)(xb + (size_t)nm * 64 + s * 32 + q * 8);
            #pragma unroll
            for (int tt = 0; tt < 4; ++tt)
                acc4[tt] = __builtin_amdgcn_mfma_f32_16x16x32_bf16(
                    af, WB[(s * 4 + tt) * 64 + lane], acc4[tt], 0, 0, 0);
        }
        #pragma unroll
        for (int s = 0; s < 2; ++s) {
            short8 af = *(const short8*)(aggS + lnl * ASTR + s * 32 + q * 8);
            #pragma unroll
            for (int tt = 0; tt < 4; ++tt)
                acc4[tt] = __builtin_amdgcn_mfma_f32_16x16x32_bf16(
                    af, WB[((2 + s) * 4 + tt) * 64 + lane], acc4[tt], 0, 0, 0);
        }

        float bb[4], gg[4], be[4];
        #pragma unroll
        for (int tt = 0; tt < 4; ++tt) {
            bb[tt] = b[tt * 16 + c];
            gg[tt] = gamma[tt * 16 + c];
            be[tt] = beta[tt * 16 + c];
        }
        #pragma unroll
        for (int r = 0; r < 4; ++r) {
            int node = nb + q * 4 + r;
            float v[4]; float s0 = 0.f, q0 = 0.f;
            #pragma unroll
            for (int tt = 0; tt < 4; ++tt) {
                float vv = acc4[tt][r] + bb[tt];
                vv = fmaxf(vv, 0.f);
                v[tt] = vv; s0 += vv; q0 += vv * vv;
            }
            #pragma unroll
            for (int o = 1; o <= 8; o <<= 1) {
                s0 += __shfl_xor(s0, o);
                q0 += __shfl_xor(q0, o);
            }
            float mu  = s0 * (1.0f / 64.0f);
            float var = q0 * (1.0f / 64.0f) - mu * mu;
            float rs  = rsqrtf(var + LN_EPS);
            if (node < N) {
                #pragma unroll
                for (int tt = 0; tt < 4; ++tt)
                    out[(size_t)node * 64 + tt * 16 + c] = (v[tt] - mu) * rs * gg[tt] + be[tt];
            }
        }
    }
}

extern "C" void kernel_launch(void* const* d_in, const int* in_sizes, int n_in,
                              void* d_out, int out_size, void* d_ws, size_t ws_size,
                              hipStream_t stream)
{
    const float* x     = (const float*)d_in[0];
    const int*   ei    = (const int*)d_in[1];
    const float* W     = (const float*)d_in[2];
    const float* b     = (const float*)d_in[3];
    const float* gamma = (const float*)d_in[4];
    const float* beta  = (const float*)d_in[5];

    int N = in_sizes[0] / 64;      // 100000
    int E = in_sizes[1] / 2;       // 1600000

    // ws (ints): cursor1[128] | cursor2[896*8] | WTB[4096] | pairs2[NBK*BC]
    //            | xb (bf16, N+1 rows: row N = zero sentinel)
    int* wsI = (int*)d_ws;
    int* cursor1 = wsI;
    int* cursor2 = wsI + 128;
    unsigned short* WTB = (unsigned short*)(wsI + 128 + 896 * CSTRIDE);
    int* pairs2 = wsI + 128 + 896 * CSTRIDE + 4096;
    unsigned short* xb = (unsigned short*)(pairs2 + (size_t)NBK * BC);

    // pairs1 lives in d_out (7.5 MB of 25.6 MB), dead after bin2; the fused
    // sortgather then overwrites d_out with the final f32 output. ei untouched.
    int* pairs1 = (int*)d_out;
    float* out = (float*)d_out;

    hipMemsetAsync(cursor1, 0, (size_t)(128 + 896 * CSTRIDE) * sizeof(int), stream);

    int b1 = (E + 4095) / 4096;        // 391
    bin1_kernel<<<b1, 256, 0, stream>>>(ei, cursor1, pairs1, W, WTB,
                                        (const float4*)x, (ushort4*)xb, E, N);

    bin2_kernel<<<NSB * CPS, 256, 0, stream>>>(cursor1, pairs1, cursor2, pairs2);

    sortgather_kernel<<<NBK, 1024, 0, stream>>>(cursor2, pairs2, xb, WTB,
                                                b, gamma, beta, out, N);
}

// Round 7
// 163.147 us; speedup vs baseline: 1.0550x; 1.0550x over previous
//
#include <hip/hip_runtime.h>

#define LN_EPS 1e-5f
#define SBSH   14             // superbucket = dst >> 14 (16384 nodes)
#define NSB    7              // ceil(100000 / 16384)
#define CAP1   268288         // per-SB capacity = 131*2048 (mean 262144 + ~13 sigma)
#define CPS    131            // CAP1 / 2048 chunks per SB (bin2 chunking)
#define BN     128            // nodes per final bucket
#define BC     2368           // bucket capacity (mean 2048 + 7 sigma, R8-proven)
#define NBK    782            // ceil(N / BN)
#define CSTRIDE 8
#define ASTR   72             // aggS row stride in bf16 (144 B -> 4-bank row shift, 2-way max)

typedef __attribute__((ext_vector_type(8))) short short8;
typedef __attribute__((ext_vector_type(8))) unsigned short ushort8;
typedef __attribute__((ext_vector_type(4))) float v4f;

__device__ __forceinline__ unsigned short f2bf(float f) {
    union { float f; unsigned u; } v; v.f = f;
    unsigned r = (v.u + 0x7fffu + ((v.u >> 16) & 1u)) >> 16;   // RNE
    return (unsigned short)r;
}
__device__ __forceinline__ float bf2f(unsigned short h) {
    union { unsigned u; float f; } v; v.u = ((unsigned)h) << 16;
    return v.f;
}

// ---------------- bin1: edges -> 7 superbuckets (+ WTB + x->bf16) ----------------
__global__ __launch_bounds__(256) void bin1_kernel(
    const int* __restrict__ ei, int* __restrict__ cursor1,
    int* __restrict__ pairs1, const float* __restrict__ W,
    unsigned short* __restrict__ WTB, const float4* __restrict__ x4,
    ushort4* __restrict__ xb4, int E, int N)
{
    __shared__ int h[64];       // [copy*8 + sb]
    __shared__ int hbase[64];
    int t = threadIdx.x;
    int cp = t & 7;

    if (blockIdx.x == 0) {
        // WTB: frag (s,tt), lane l, elem j <- W[o=tt*16+(l&15)][k=s*32+(l>>4)*8+j]
        for (int i = t; i < 8192; i += 256) {
            int j = i & 7, l = (i >> 3) & 63, st = i >> 9;
            int s = st >> 2, tt = st & 3;
            WTB[i] = f2bf(W[(tt * 16 + (l & 15)) * 128 + s * 32 + (l >> 4) * 8 + j]);
        }
    }
    {   // grid-stride x -> bf16
        int total4 = N * 16;
        for (int i = blockIdx.x * 256 + t; i < total4; i += gridDim.x * 256) {
            float4 v = x4[i];
            ushort4 u;
            u.x = f2bf(v.x); u.y = f2bf(v.y); u.z = f2bf(v.z); u.w = f2bf(v.w);
            xb4[i] = u;
        }
    }

    for (int i = t; i < 64; i += 256) h[i] = 0;
    __syncthreads();
    int e0 = blockIdx.x * 4096;
    int dstA[16], srcA[16], rkA[16];
    #pragma unroll
    for (int i = 0; i < 16; ++i) {
        int e = e0 + i * 256 + t;
        int dst = 0, src = 0, rk = -1;
        if (e < E) {
            dst = ei[e]; src = ei[E + e];
            if ((unsigned)dst < (unsigned)N) {
                rk = atomicAdd(&h[cp * 8 + (dst >> SBSH)], 1);
                if ((unsigned)src >= (unsigned)N) src = 0;   // replay-safe clamp
            } else { dst = 0; }
        }
        dstA[i] = dst; srcA[i] = src; rkA[i] = rk;
    }
    __syncthreads();
    if (t < 8) {    // per sb: total over copies, one global reservation, copy prefixes
        int tot = 0;
        #pragma unroll
        for (int c = 0; c < 8; ++c) tot += h[c * 8 + t];
        int gb = tot ? atomicAdd(&cursor1[t * 16], tot) : 0;
        int run = gb;
        #pragma unroll
        for (int c = 0; c < 8; ++c) { hbase[c * 8 + t] = run; run += h[c * 8 + t]; }
    }
    __syncthreads();
    #pragma unroll
    for (int i = 0; i < 16; ++i) {
        if (rkA[i] >= 0) {
            int sb = dstA[i] >> SBSH;
            int slot = hbase[cp * 8 + sb] + rkA[i];
            if (slot < CAP1)
                pairs1[(size_t)sb * CAP1 + slot] = ((dstA[i] & 16383) << 17) | srcA[i];
        }
    }
}

// ---------------- bin2: superbucket chunk -> 128-node buckets ----------------
__global__ __launch_bounds__(256) void bin2_kernel(
    const int* __restrict__ cursor1, const int* __restrict__ pairs1,
    int* __restrict__ cursor2, int* __restrict__ pairs2)
{
    __shared__ int h[128], hbase[128];
    int t = threadIdx.x;
    int sb = blockIdx.x / CPS;
    int off0 = (blockIdx.x % CPS) * 2048;
    int tot = cursor1[sb * 16]; if (tot > CAP1) tot = CAP1;
    int m = tot - off0;
    if (m <= 0) return;                    // block-uniform
    if (m > 2048) m = 2048;
    if (t < 128) h[t] = 0;
    __syncthreads();
    const int* p1 = pairs1 + (size_t)sb * CAP1 + off0;
    int pvA[8], rkA[8];
    #pragma unroll
    for (int i = 0; i < 8; ++i) {
        int idx = i * 256 + t;
        int pv = 0, rk = -1;
        if (idx < m) { pv = p1[idx]; rk = atomicAdd(&h[(pv >> 24) & 127], 1); }
        pvA[i] = pv; rkA[i] = rk;
    }
    __syncthreads();
    if (t < 128) {
        int c = h[t];
        hbase[t] = c ? atomicAdd(&cursor2[(sb * 128 + t) * CSTRIDE], c) : 0;
    }
    __syncthreads();
    #pragma unroll
    for (int i = 0; i < 8; ++i) {
        if (rkA[i] >= 0) {
            int bl = (pvA[i] >> 24) & 127;
            int g = sb * 128 + bl;
            int slot = hbase[bl] + rkA[i];
            if (g < NBK && slot < BC)
                pairs2[(size_t)g * BC + slot] = pvA[i] & 0xFFFFFF;
        }
    }
}

// ---- fused sortgather + linear + ReLU + LN (v5: src-slice-ordered gather) ----
// Round-5 post-mortem: depth is NOT the limiter (Little's law gives 20x the
// observed 7.8 B/cy/CU); the limiter is per-CU miss-tracking x miss LATENCY,
// and FETCH=81MB on a 12.8MB working set says the random src order misses L2.
// v5 attacks latency: counting-sort key widened to (pv>>14)&1023 -- bits 14..23
// of pv are src[16:14]||dl7, i.e. dst-major, src-SLICE-minor at zero cost.
// Each slice = 16K rows = 2MB < 4MB per-XCD L2; all blocks sweep slices in the
// same order, so gather misses become L2 hits (~200cy) instead of LLC/HBM
// (~600-900cy). Gather loop itself = round-3-proven 4-deep chained form.
__global__ __launch_bounds__(1024, 8) void sortgather_kernel(
    const int* __restrict__ cursor2, const int* __restrict__ pairs2,
    const unsigned short* __restrict__ xb, const unsigned short* __restrict__ WTB,
    const float* __restrict__ b, const float* __restrict__ gamma,
    const float* __restrict__ beta, float* __restrict__ out, int N)
{
    __shared__ int srcS[BC];                         // 9.47 KB
    __shared__ int h[1024];                          // 4 KB: (dl7,srchi3) hist -> excl off
    __shared__ int wsum[16];
    __shared__ __align__(16) unsigned short aggS[BN * ASTR];   // 18 KB
    int t = threadIdx.x;
    int g = blockIdx.x;
    int bsize = cursor2[g * CSTRIDE]; if (bsize > BC) bsize = BC;
    const int* pb = pairs2 + (size_t)g * BC;

    h[t] = 0;
    __syncthreads();
    // single histogram+rank pass over 1024 (dst,src-slice) keys
    int pvA[3], rkA[3];
    #pragma unroll
    for (int i = 0; i < 3; ++i) {
        int idx = i * 1024 + t;
        int pv = 0, rk = -1;
        if (idx < bsize) { pv = pb[idx]; rk = atomicAdd(&h[(pv >> 14) & 1023], 1); }
        pvA[i] = pv; rkA[i] = rk;
    }
    __syncthreads();
    int lane = t & 63, wv = t >> 6;
    // hierarchical exclusive scan over 1024 bins, in place:
    // wave wv scans its 64 bins; wave totals scanned by wave 0; recombine.
    int c = h[wv * 64 + lane];
    int v = c;
    #pragma unroll
    for (int d = 1; d < 64; d <<= 1) {
        int u = __shfl_up(v, d);
        if (lane >= d) v += u;
    }
    if (lane == 63) wsum[wv] = v;
    __syncthreads();
    if (t < 16) {
        int cw = wsum[t];
        int vw = cw;
        #pragma unroll
        for (int d = 1; d < 16; d <<= 1) {
            int u = __shfl_up(vw, d);
            if (t >= d) vw += u;
        }
        wsum[t] = vw - cw;               // exclusive wave base
    }
    __syncthreads();
    h[wv * 64 + lane] = v - c + wsum[wv];   // exclusive bin offset
    __syncthreads();
    // scatter: srcS ordered by dst, then by src-slice within dst
    #pragma unroll
    for (int i = 0; i < 3; ++i) {
        if (rkA[i] >= 0) {
            int key = (pvA[i] >> 14) & 1023;
            srcS[h[key] + rkA[i]] = pvA[i] & 0x1FFFF;
        }
    }
    __syncthreads();

    int g8 = lane >> 3, f8 = lane & 7;       // 16 waves x 8 groups = 128 nodes
    int ln = wv * 8 + g8;                    // this group's node (bucket-local)
    int base = h[ln * 8];
    int end  = (ln == 127) ? bsize : h[ln * 8 + 8];
    int deg  = end - base;

    float acc[8];
    #pragma unroll
    for (int k = 0; k < 8; ++k) acc[k] = 0.f;

    int j = 0;
    for (; j + 4 <= deg; j += 4) {           // 4 loads in flight per group (R3-proven)
        int s0 = srcS[base + j];
        int s1 = srcS[base + j + 1];
        int s2 = srcS[base + j + 2];
        int s3 = srcS[base + j + 3];
        short8 a0 = *(const short8*)(xb + (size_t)s0 * 64 + f8 * 8);
        short8 a1 = *(const short8*)(xb + (size_t)s1 * 64 + f8 * 8);
        short8 a2 = *(const short8*)(xb + (size_t)s2 * 64 + f8 * 8);
        short8 a3 = *(const short8*)(xb + (size_t)s3 * 64 + f8 * 8);
        #pragma unroll
        for (int k = 0; k < 8; ++k) acc[k] += bf2f((unsigned short)a0[k]);
        #pragma unroll
        for (int k = 0; k < 8; ++k) acc[k] += bf2f((unsigned short)a1[k]);
        #pragma unroll
        for (int k = 0; k < 8; ++k) acc[k] += bf2f((unsigned short)a2[k]);
        #pragma unroll
        for (int k = 0; k < 8; ++k) acc[k] += bf2f((unsigned short)a3[k]);
    }
    for (; j < deg; ++j) {
        int s0 = srcS[base + j];
        short8 a0 = *(const short8*)(xb + (size_t)s0 * 64 + f8 * 8);
        #pragma unroll
        for (int k = 0; k < 8; ++k) acc[k] += bf2f((unsigned short)a0[k]);
    }

    {   // agg (mean) -> LDS bf16, row = bucket-local node, stride 72
        float inv = 1.0f / fmaxf((float)deg, 1.0f);
        ushort8 r;
        #pragma unroll
        for (int k = 0; k < 8; ++k) r[k] = f2bf(acc[k] * inv);
        *(ushort8*)(aggS + ln * ASTR + f8 * 8) = r;   // 144-B rows: 16-B aligned
    }
    __syncthreads();

    // ---- linear epilogue: waves 0..7, wave wv -> nodes [g*128+wv*16, +16) ----
    if (wv < 8) {
        int cc = lane & 15, q = lane >> 4;
        int nb = g * BN + wv * 16;
        int nm = nb + cc; if (nm >= N) nm = N - 1;
        int lnl = wv * 16 + cc;              // bucket-local node for aggS

        const short8* WB = (const short8*)WTB;
        v4f acc4[4];
        #pragma unroll
        for (int tt = 0; tt < 4; ++tt) acc4[tt] = 0.f;

        #pragma unroll
        for (int s = 0; s < 2; ++s) {
            short8 af = *(const short8*)(xb + (size_t)nm * 64 + s * 32 + q * 8);
            #pragma unroll
            for (int tt = 0; tt < 4; ++tt)
                acc4[tt] = __builtin_amdgcn_mfma_f32_16x16x32_bf16(
                    af, WB[(s * 4 + tt) * 64 + lane], acc4[tt], 0, 0, 0);
        }
        #pragma unroll
        for (int s = 0; s < 2; ++s) {
            short8 af = *(const short8*)(aggS + lnl * ASTR + s * 32 + q * 8);
            #pragma unroll
            for (int tt = 0; tt < 4; ++tt)
                acc4[tt] = __builtin_amdgcn_mfma_f32_16x16x32_bf16(
                    af, WB[((2 + s) * 4 + tt) * 64 + lane], acc4[tt], 0, 0, 0);
        }

        float bb[4], gg[4], be[4];
        #pragma unroll
        for (int tt = 0; tt < 4; ++tt) {
            bb[tt] = b[tt * 16 + cc];
            gg[tt] = gamma[tt * 16 + cc];
            be[tt] = beta[tt * 16 + cc];
        }
        #pragma unroll
        for (int r = 0; r < 4; ++r) {
            int node = nb + q * 4 + r;
            float vv4[4]; float s0 = 0.f, q0 = 0.f;
            #pragma unroll
            for (int tt = 0; tt < 4; ++tt) {
                float vv = acc4[tt][r] + bb[tt];
                vv = fmaxf(vv, 0.f);
                vv4[tt] = vv; s0 += vv; q0 += vv * vv;
            }
            #pragma unroll
            for (int o = 1; o <= 8; o <<= 1) {
                s0 += __shfl_xor(s0, o);
                q0 += __shfl_xor(q0, o);
            }
            float mu  = s0 * (1.0f / 64.0f);
            float var = q0 * (1.0f / 64.0f) - mu * mu;
            float rs  = rsqrtf(var + LN_EPS);
            if (node < N) {
                #pragma unroll
                for (int tt = 0; tt < 4; ++tt)
                    out[(size_t)node * 64 + tt * 16 + cc] = (vv4[tt] - mu) * rs * gg[tt] + be[tt];
            }
        }
    }
}

extern "C" void kernel_launch(void* const* d_in, const int* in_sizes, int n_in,
                              void* d_out, int out_size, void* d_ws, size_t ws_size,
                              hipStream_t stream)
{
    const float* x     = (const float*)d_in[0];
    const int*   ei    = (const int*)d_in[1];
    const float* W     = (const float*)d_in[2];
    const float* b     = (const float*)d_in[3];
    const float* gamma = (const float*)d_in[4];
    const float* beta  = (const float*)d_in[5];

    int N = in_sizes[0] / 64;      // 100000
    int E = in_sizes[1] / 2;       // 1600000

    // ws (ints): cursor1[128] | cursor2[896*8] | WTB[4096] | pairs2[NBK*BC] | xb (bf16)
    int* wsI = (int*)d_ws;
    int* cursor1 = wsI;
    int* cursor2 = wsI + 128;
    unsigned short* WTB = (unsigned short*)(wsI + 128 + 896 * CSTRIDE);
    int* pairs2 = wsI + 128 + 896 * CSTRIDE + 4096;
    unsigned short* xb = (unsigned short*)(pairs2 + (size_t)NBK * BC);

    // pairs1 lives in d_out (7.5 MB of 25.6 MB), dead after bin2; the fused
    // sortgather then overwrites d_out with the final f32 output. ei untouched.
    int* pairs1 = (int*)d_out;
    float* out = (float*)d_out;

    hipMemsetAsync(cursor1, 0, (size_t)(128 + 896 * CSTRIDE) * sizeof(int), stream);

    int b1 = (E + 4095) / 4096;        // 391
    bin1_kernel<<<b1, 256, 0, stream>>>(ei, cursor1, pairs1, W, WTB,
                                        (const float4*)x, (ushort4*)xb, E, N);

    bin2_kernel<<<NSB * CPS, 256, 0, stream>>>(cursor1, pairs1, cursor2, pairs2);

    sortgather_kernel<<<NBK, 1024, 0, stream>>>(cursor2, pairs2, xb, WTB,
                                                b, gamma, beta, out, N);
}